// Round 6
// baseline (460.986 us; speedup 1.0000x reference)
//
#include <hip/hip_runtime.h>
#include <math.h>

#define EPS_BN 1e-5f
#define MAXNB 512  // max coarse buckets (N <= 131072); also assumes N < 2^24

typedef __attribute__((ext_vector_type(8))) short bf16x8;
typedef __attribute__((ext_vector_type(4))) float f32x4;

__device__ __forceinline__ ushort f2bf(float f) {
    uint u = __float_as_uint(f);
    u += 0x7FFF + ((u >> 16) & 1);  // RTN-even
    return (ushort)(u >> 16);
}
__device__ __forceinline__ float bf2f(uint h) {
    return __uint_as_float(h << 16);
}

// ================= bucketed CSR build =================
__global__ __launch_bounds__(256) void chist_k(const int* __restrict__ dst,
                                               int* __restrict__ bcnt, int nE, int NB) {
    __shared__ int s[MAXNB];
    for (int i = threadIdx.x; i < NB; i += 256) s[i] = 0;
    __syncthreads();
    int base = blockIdx.x * 4096;
#pragma unroll
    for (int i = 0; i < 16; i++) {
        int e = base + i * 256 + threadIdx.x;
        if (e < nE) atomicAdd(&s[dst[e] >> 8], 1);
    }
    __syncthreads();
    for (int i = threadIdx.x; i < NB; i += 256)
        if (s[i]) atomicAdd(&bcnt[i], s[i]);
}

__global__ __launch_bounds__(512) void cscan_k(const int* __restrict__ bcnt,
                                               int* __restrict__ bstart,
                                               int* __restrict__ bcur,
                                               int* __restrict__ rowstart,
                                               int NB, int nE, int N) {
    __shared__ int s[512];
    int t = threadIdx.x;
    int c = (t < NB) ? bcnt[t] : 0;
    s[t] = c;
    __syncthreads();
    for (int off = 1; off < 512; off <<= 1) {
        int v = (t >= off) ? s[t - off] : 0;
        __syncthreads();
        s[t] += v;
        __syncthreads();
    }
    int ex = s[t] - c;
    if (t < NB) {
        bstart[t] = ex;
        bcur[t] = ex;
    }
    if (t == 0) {
        bstart[NB] = nE;
        rowstart[N] = nE;
    }
}

// phase A: tile-ranked scatter; coarse entry packed: src | (dst&255)<<24
__global__ __launch_bounds__(256) void bucketA_k(const int* __restrict__ src,
                                                 const int* __restrict__ dst,
                                                 int* __restrict__ bcur,
                                                 int* __restrict__ coarse, int nE, int NB) {
    __shared__ int cnt[MAXNB];
    __shared__ int basix[MAXNB];
    const int tid = threadIdx.x;
    for (int i = tid; i < NB; i += 256) cnt[i] = 0;
    __syncthreads();
    int base = blockIdx.x * 4096;
    int es[16], ed[16], rk[16];
#pragma unroll
    for (int i = 0; i < 16; i++) {
        int e = base + i * 256 + tid;
        if (e < nE) {
            es[i] = src[e];
            ed[i] = dst[e];
            rk[i] = atomicAdd(&cnt[ed[i] >> 8], 1);
        } else {
            ed[i] = -1;
        }
    }
    __syncthreads();
    for (int i = tid; i < NB; i += 256)
        if (cnt[i]) basix[i] = atomicAdd(&bcur[i], cnt[i]);
    __syncthreads();
#pragma unroll
    for (int i = 0; i < 16; i++) {
        if (ed[i] >= 0)
            coarse[basix[ed[i] >> 8] + rk[i]] = es[i] | ((ed[i] & 255) << 24);
    }
}

// phase B: per-bucket exact CSR with per-(row, src-bucket) counting sort.
// col within each row comes out sorted by src>>13 -> gather gets src-locality.
__global__ __launch_bounds__(256) void bucketB_k(const int* __restrict__ coarse,
                                                 const int* __restrict__ bstart,
                                                 int* __restrict__ rowstart,
                                                 int* __restrict__ col,
                                                 float* __restrict__ dinv, int N) {
    __shared__ int cnt[4096];   // [row 0..255][srcbucket 0..15]
    __shared__ int rtot[256];
    const int tid = threadIdx.x;
    const int b = blockIdx.x;
    const int beg = bstart[b], end = bstart[b + 1];
#pragma unroll
    for (int i = 0; i < 16; i++) cnt[tid * 16 + i] = 0;
    __syncthreads();
    for (int p = beg + tid; p < end; p += 256) {
        int v = coarse[p];
        int row = ((uint)v) >> 24;
        int bkt = (v & 0xFFFFFF) >> 13;
        atomicAdd(&cnt[row * 16 + bkt], 1);
    }
    __syncthreads();
    // per-row exclusive prefix over the 16 buckets (thread tid owns row tid)
    int run = 0;
#pragma unroll
    for (int i = 0; i < 16; i++) {
        int c = cnt[tid * 16 + i];
        cnt[tid * 16 + i] = run;
        run += c;
    }
    rtot[tid] = run;  // degree of row tid
    __syncthreads();
    for (int off = 1; off < 256; off <<= 1) {
        int v = (tid >= off) ? rtot[tid - off] : 0;
        __syncthreads();
        rtot[tid] += v;
        __syncthreads();
    }
    int ex = rtot[tid] - run;  // exclusive row offset within bucket
    int node = b * 256 + tid;
    if (node < N) {
        rowstart[node] = beg + ex;
        dinv[node] = rsqrtf((float)run + 1.0f);  // +1 = self loop
    }
#pragma unroll
    for (int i = 0; i < 16; i++) cnt[tid * 16 + i] += ex;  // absolute cursors
    __syncthreads();
    for (int p = beg + tid; p < end; p += 256) {
        int v = coarse[p];
        int row = ((uint)v) >> 24;
        int src = v & 0xFFFFFF;
        int o = atomicAdd(&cnt[row * 16 + (src >> 13)], 1);
        col[beg + o] = src;
    }
}

// ================= weight prep =================
__global__ __launch_bounds__(256) void prep_wt_all_k(const float* __restrict__ W1,
                                                     const float* __restrict__ W2,
                                                     const float* __restrict__ W3,
                                                     const float* __restrict__ W4,
                                                     ushort* __restrict__ T1,
                                                     ushort* __restrict__ T2,
                                                     ushort* __restrict__ T3,
                                                     ushort* __restrict__ T4) {
    int which = blockIdx.x >> 6;
    const float* W = (which == 0) ? W1 : (which == 1) ? W2 : (which == 2) ? W3 : W4;
    ushort* T = (which == 0) ? T1 : (which == 1) ? T2 : (which == 2) ? T3 : T4;
    int i = (blockIdx.x & 63) * 256 + threadIdx.x;  // < 16384
    int n = i >> 7, k = i & 127;
    T[n * 128 + k] = f2bf(W[k * 128 + n]);
}

// ============ gather conv over pre-scaled hs = dinv[s]*h[s] ============
// out = relu(bn(dd*(hs[d] + sum_s hs[s]) + bias)); narrow walk: 2 ch/lane,
// 4 consecutive (src-sorted) edges in flight -> small src window -> L2 hits.
__global__ __launch_bounds__(256) void gather_k(const ushort* __restrict__ hs,
                                                const int* __restrict__ rowstart,
                                                const int* __restrict__ col,
                                                const float* __restrict__ dinv,
                                                const float* __restrict__ bias,
                                                const float* __restrict__ g,
                                                const float* __restrict__ be,
                                                const float* __restrict__ mn,
                                                const float* __restrict__ vr,
                                                ushort* __restrict__ out, int n) {
    int node = blockIdx.x * 4 + (threadIdx.x >> 6);
    if (node >= n) return;
    int lane = threadIdx.x & 63;
    int c = lane * 2;
    int beg = rowstart[node], end = rowstart[node + 1];
    float dd = dinv[node];
    uint hp = *(const uint*)&hs[(size_t)node * 128 + c];
    float acc0 = bf2f(hp & 0xffffu);  // self loop: hs[d]
    float acc1 = bf2f(hp >> 16);
    int p = beg;
    for (; p + 3 < end; p += 4) {
        int s0 = __builtin_nontemporal_load(col + p);
        int s1 = __builtin_nontemporal_load(col + p + 1);
        int s2 = __builtin_nontemporal_load(col + p + 2);
        int s3 = __builtin_nontemporal_load(col + p + 3);
        uint a = *(const uint*)&hs[(size_t)s0 * 128 + c];
        uint b = *(const uint*)&hs[(size_t)s1 * 128 + c];
        uint d2 = *(const uint*)&hs[(size_t)s2 * 128 + c];
        uint d3 = *(const uint*)&hs[(size_t)s3 * 128 + c];
        acc0 += bf2f(a & 0xffffu) + bf2f(b & 0xffffu);
        acc1 += bf2f(a >> 16) + bf2f(b >> 16);
        acc0 += bf2f(d2 & 0xffffu) + bf2f(d3 & 0xffffu);
        acc1 += bf2f(d2 >> 16) + bf2f(d3 >> 16);
    }
    for (; p < end; p++) {
        int s0 = __builtin_nontemporal_load(col + p);
        uint a = *(const uint*)&hs[(size_t)s0 * 128 + c];
        acc0 += bf2f(a & 0xffffu);
        acc1 += bf2f(a >> 16);
    }
    acc0 *= dd;
    acc1 *= dd;
    float sc0 = g[c] * rsqrtf(vr[c] + EPS_BN);
    float sc1 = g[c + 1] * rsqrtf(vr[c + 1] + EPS_BN);
    float o0 = fmaxf((acc0 + bias[c] - mn[c]) * sc0 + be[c], 0.0f);
    float o1 = fmaxf((acc1 + bias[c + 1] - mn[c + 1]) * sc1 + be[c + 1], 0.0f);
    uint r = (uint)f2bf(o0) | ((uint)f2bf(o1) << 16);
    *(uint*)&out[(size_t)node * 128 + c] = r;
}

// ============ MFMA GEMM: Y = X(n,128) @ W(128,128), fused epilogues ============
// MODE 0: hs = dinv[row]*v -> bf16   MODE 1: relu(bn(v+bias)) -> bf16
// MODE 2: relu(v+bias) -> f32, PLUS fused head: pred = softplus(h1 @ Wo + bo)
// F32IN: input X is f32 (converted to bf16 during LDS staging)
template <int MODE, int F32IN>
__global__ __launch_bounds__(256) void mfma_gemm_k(const void* __restrict__ Xin,
                                                   const ushort* __restrict__ Wt,
                                                   const float* __restrict__ dinvp,
                                                   const float* __restrict__ bias,
                                                   const float* __restrict__ g,
                                                   const float* __restrict__ be,
                                                   const float* __restrict__ mn,
                                                   const float* __restrict__ vr,
                                                   const float* __restrict__ Wo,
                                                   const float* __restrict__ bo,
                                                   float* __restrict__ pred,
                                                   void* __restrict__ Y, int nrows) {
    constexpr int LDK = 136;  // 128 + 8 pad
    __shared__ ushort sX[64 * LDK];
    __shared__ ushort sW[128 * LDK];
    __shared__ float red[64];
    __shared__ float sD[64];
    const int tid = threadIdx.x;
    const int row0 = blockIdx.x * 64;

#pragma unroll
    for (int i = 0; i < 8; i++) {
        int c = tid + i * 256;
        int r = c >> 4, o = c & 15;
        *(int4*)&sW[r * LDK + o * 8] = *(const int4*)&Wt[r * 128 + o * 8];
    }
    if (F32IN) {
        const float* Xf = (const float*)Xin;
#pragma unroll
        for (int i = 0; i < 8; i++) {
            int c = tid + i * 256;      // 2048 float4-chunks
            int r = c >> 5, o = c & 31; // 32 float4 per row
            int rg = row0 + r;
            if (rg >= nrows) rg = nrows - 1;
            float4 v = *(const float4*)&Xf[(size_t)rg * 128 + o * 4];
            ushort4 u = {f2bf(v.x), f2bf(v.y), f2bf(v.z), f2bf(v.w)};
            *(ushort4*)&sX[r * LDK + o * 4] = u;
        }
    } else {
        const ushort* Xb = (const ushort*)Xin;
#pragma unroll
        for (int i = 0; i < 4; i++) {
            int c = tid + i * 256;
            int r = c >> 4, o = c & 15;
            int rg = row0 + r;
            if (rg >= nrows) rg = nrows - 1;
            *(int4*)&sX[r * LDK + o * 8] = *(const int4*)&Xb[(size_t)rg * 128 + o * 8];
        }
    }
    if (MODE == 2 && tid < 64) red[tid] = 0.0f;
    if (MODE == 0 && tid < 64) {
        int rg = row0 + tid;
        sD[tid] = dinvp[(rg < nrows) ? rg : (nrows - 1)];
    }
    __syncthreads();

    const int wave = tid >> 6, lane = tid & 63;
    const int rw = (wave >> 1) * 32;
    const int cw = (wave & 1) * 64;
    const int lm = lane & 15, lq = lane >> 4;

    f32x4 acc[2][4];
#pragma unroll
    for (int tr = 0; tr < 2; tr++)
#pragma unroll
        for (int tc = 0; tc < 4; tc++) acc[tr][tc] = (f32x4){0.f, 0.f, 0.f, 0.f};

#pragma unroll
    for (int ks = 0; ks < 4; ks++) {
        int kb = ks * 32 + lq * 8;
        bf16x8 a[2], b[4];
#pragma unroll
        for (int tr = 0; tr < 2; tr++)
            a[tr] = *(bf16x8*)&sX[(rw + tr * 16 + lm) * LDK + kb];
#pragma unroll
        for (int tc = 0; tc < 4; tc++)
            b[tc] = *(bf16x8*)&sW[(cw + tc * 16 + lm) * LDK + kb];
#pragma unroll
        for (int tr = 0; tr < 2; tr++)
#pragma unroll
            for (int tc = 0; tc < 4; tc++)
                acc[tr][tc] = __builtin_amdgcn_mfma_f32_16x16x32_bf16(a[tr], b[tc],
                                                                      acc[tr][tc], 0, 0, 0);
    }

    float part[8];
    if (MODE == 2) {
#pragma unroll
        for (int i = 0; i < 8; i++) part[i] = 0.0f;
    }
#pragma unroll
    for (int tc = 0; tc < 4; tc++) {
        int c = cw + tc * 16 + lm;
        float psc, psh;
        if (MODE == 1) {
            float sc = g[c] * rsqrtf(vr[c] + EPS_BN);
            psc = sc;
            psh = be[c] + (bias[c] - mn[c]) * sc;
        } else if (MODE == 2) {
            psc = 1.0f;
            psh = bias[c];
        } else {
            psc = 1.0f;
            psh = 0.0f;
        }
        float woc = (MODE == 2) ? Wo[c] : 0.0f;
#pragma unroll
        for (int tr = 0; tr < 2; tr++) {
#pragma unroll
            for (int r = 0; r < 4; r++) {
                int lrow = rw + tr * 16 + lq * 4 + r;
                int row = row0 + lrow;
                if (row < nrows) {
                    float v;
                    if (MODE == 0) {
                        v = acc[tr][tc][r] * sD[lrow];  // hs = dinv * (X@W)
                    } else {
                        v = acc[tr][tc][r] * psc + psh;
                        v = fmaxf(v, 0.0f);
                    }
                    if (MODE == 2) {
                        ((float*)Y)[(size_t)row * 128 + c] = v;
                        part[tr * 4 + r] = fmaf(v, woc, part[tr * 4 + r]);
                    } else {
                        ((ushort*)Y)[(size_t)row * 128 + c] = f2bf(v);
                    }
                }
            }
        }
    }
    if (MODE == 2) {
#pragma unroll
        for (int tr = 0; tr < 2; tr++)
#pragma unroll
            for (int r = 0; r < 4; r++)
                atomicAdd(&red[rw + tr * 16 + lq * 4 + r], part[tr * 4 + r]);
        __syncthreads();
        if (tid < 64) {
            int row = row0 + tid;
            if (row < nrows) {
                float xv = red[tid] + bo[0];
                pred[row] = fmaxf(xv, 0.0f) + log1pf(expf(-fabsf(xv)));  // softplus
            }
        }
    }
}

extern "C" void kernel_launch(void* const* d_in, const int* in_sizes, int n_in,
                              void* d_out, int out_size, void* d_ws, size_t ws_size,
                              hipStream_t stream) {
    const float* x = (const float*)d_in[0];
    const int* ei = (const int*)d_in[1];
    const int N = in_sizes[0] / 128;
    const int E = in_sizes[1] / 2;
    const int* srcv = ei;
    const int* dstv = ei + E;
    const float* W1 = (const float*)d_in[2];  const float* b1 = (const float*)d_in[3];
    const float* W2 = (const float*)d_in[4];  const float* b2 = (const float*)d_in[5];
    const float* Wf1 = (const float*)d_in[6]; const float* bf1 = (const float*)d_in[7];
    const float* Wf2 = (const float*)d_in[8]; const float* bf2 = (const float*)d_in[9];
    const float* Wo = (const float*)d_in[10]; const float* bo = (const float*)d_in[11];
    const float* g1 = (const float*)d_in[12], *be1 = (const float*)d_in[13],
               *m1 = (const float*)d_in[14], *v1 = (const float*)d_in[15];
    const float* g2 = (const float*)d_in[16], *be2 = (const float*)d_in[17],
               *m2 = (const float*)d_in[18], *v2 = (const float*)d_in[19];
    const float* g3 = (const float*)d_in[20], *be3 = (const float*)d_in[21],
               *m3 = (const float*)d_in[22], *v3 = (const float*)d_in[23];

    // ---- workspace carve-up ----
    char* ws = (char*)d_ws;
    size_t off = 0;
    auto carve = [&](size_t bytes) {
        char* p = ws + off;
        off = (off + bytes + 255) & ~(size_t)255;
        return p;
    };
    const int NB = (N + 255) >> 8;
    int* bcnt = (int*)carve((size_t)MAXNB * 4);
    int* bstart = (int*)carve((size_t)(MAXNB + 1) * 4);
    int* bcur = (int*)carve((size_t)MAXNB * 4);
    int* rowstart = (int*)carve((size_t)(N + 1) * 4);
    int* col = (int*)carve((size_t)E * 4);
    int* coarse = (int*)carve((size_t)E * 4);
    float* dinv = (float*)carve((size_t)N * 4);
    ushort* bufA = (ushort*)carve((size_t)N * 128 * 2);
    ushort* bufB = (ushort*)carve((size_t)N * 128 * 2);
    ushort* Wt1 = (ushort*)carve(128 * 128 * 2);
    ushort* Wt2 = (ushort*)carve(128 * 128 * 2);
    ushort* Wtf1 = (ushort*)carve(128 * 128 * 2);
    ushort* Wtf2 = (ushort*)carve(128 * 128 * 2);

    float* out_pred = (float*)d_out;
    float* out_h1 = out_pred + N;

    const int gblocks = (N + 63) / 64;
    const int tblocks = (E + 4095) / 4096;
    const int wblocks = (N + 3) / 4;

    // ---- bucketed CSR build ----
    hipMemsetAsync(bcnt, 0, (size_t)MAXNB * 4, stream);
    chist_k<<<tblocks, 256, 0, stream>>>(dstv, bcnt, E, NB);
    cscan_k<<<1, 512, 0, stream>>>(bcnt, bstart, bcur, rowstart, NB, E, N);
    bucketA_k<<<tblocks, 256, 0, stream>>>(srcv, dstv, bcur, coarse, E, NB);
    bucketB_k<<<NB, 256, 0, stream>>>(coarse, bstart, rowstart, col, dinv, N);

    // ---- weight prep ----
    prep_wt_all_k<<<256, 256, 0, stream>>>(W1, W2, Wf1, Wf2, Wt1, Wt2, Wtf1, Wtf2);

    // layer 1: hs1 = dinv * (x@W1);  h = relu(bn1(dd*(sum hs1) + b1))
    mfma_gemm_k<0, 1><<<gblocks, 256, 0, stream>>>(x, Wt1, dinv, nullptr, nullptr,
                                                   nullptr, nullptr, nullptr, nullptr,
                                                   nullptr, nullptr, bufA, N);
    gather_k<<<wblocks, 256, 0, stream>>>(bufA, rowstart, col, dinv, b1, g1, be1, m1, v1,
                                          bufB, N);

    // layer 2
    mfma_gemm_k<0, 0><<<gblocks, 256, 0, stream>>>(bufB, Wt2, dinv, nullptr, nullptr,
                                                   nullptr, nullptr, nullptr, nullptr,
                                                   nullptr, nullptr, bufA, N);
    gather_k<<<wblocks, 256, 0, stream>>>(bufA, rowstart, col, dinv, b2, g2, be2, m2, v2,
                                          bufB, N);

    // layer 3: h = relu(bn3(h@Wf1 + bf1))
    mfma_gemm_k<1, 0><<<gblocks, 256, 0, stream>>>(bufB, Wtf1, nullptr, bf1, g3, be3, m3,
                                                   v3, nullptr, nullptr, nullptr, bufA, N);

    // layer 4 + head: h1 = relu(h@Wf2 + bf2) -> f32 d_out; pred = softplus(h1@Wo+bo)
    mfma_gemm_k<2, 0><<<gblocks, 256, 0, stream>>>(bufA, Wtf2, nullptr, bf2, nullptr,
                                                   nullptr, nullptr, nullptr, Wo, bo,
                                                   out_pred, out_h1, N);
}

// Round 7
// 418.548 us; speedup vs baseline: 1.1014x; 1.1014x over previous
//
#include <hip/hip_runtime.h>
#include <math.h>

#define EPS_BN 1e-5f
#define MAXNB 512  // max coarse buckets (N <= 131072); also assumes N < 2^24

typedef __attribute__((ext_vector_type(8))) short bf16x8;
typedef __attribute__((ext_vector_type(4))) float f32x4;
typedef __attribute__((ext_vector_type(2))) float f32x2;

__device__ __forceinline__ ushort f2bf(float f) {
    uint u = __float_as_uint(f);
    u += 0x7FFF + ((u >> 16) & 1);  // RTN-even
    return (ushort)(u >> 16);
}
__device__ __forceinline__ float bf2f(uint h) {
    return __uint_as_float(h << 16);
}
__device__ __forceinline__ unsigned char f2fp8(float v) {
    uint q = __builtin_amdgcn_cvt_pk_fp8_f32(v, v, 0, false);
    return (unsigned char)(q & 0xff);
}

// ================= bucketed CSR build =================
__global__ __launch_bounds__(256) void chist_k(const int* __restrict__ dst,
                                               int* __restrict__ bcnt, int nE, int NB) {
    __shared__ int s[MAXNB];
    for (int i = threadIdx.x; i < NB; i += 256) s[i] = 0;
    __syncthreads();
    int base = blockIdx.x * 4096;
#pragma unroll
    for (int i = 0; i < 16; i++) {
        int e = base + i * 256 + threadIdx.x;
        if (e < nE) atomicAdd(&s[dst[e] >> 8], 1);
    }
    __syncthreads();
    for (int i = threadIdx.x; i < NB; i += 256)
        if (s[i]) atomicAdd(&bcnt[i], s[i]);
}

__global__ __launch_bounds__(512) void cscan_k(const int* __restrict__ bcnt,
                                               int* __restrict__ bstart,
                                               int* __restrict__ bcur,
                                               int* __restrict__ rowstart,
                                               int NB, int nE, int N) {
    __shared__ int s[512];
    int t = threadIdx.x;
    int c = (t < NB) ? bcnt[t] : 0;
    s[t] = c;
    __syncthreads();
    for (int off = 1; off < 512; off <<= 1) {
        int v = (t >= off) ? s[t - off] : 0;
        __syncthreads();
        s[t] += v;
        __syncthreads();
    }
    int ex = s[t] - c;
    if (t < NB) {
        bstart[t] = ex;
        bcur[t] = ex;
    }
    if (t == 0) {
        bstart[NB] = nE;
        rowstart[N] = nE;
    }
}

// phase A: tile-ranked scatter; coarse entry packed: src | (dst&255)<<24
__global__ __launch_bounds__(256) void bucketA_k(const int* __restrict__ src,
                                                 const int* __restrict__ dst,
                                                 int* __restrict__ bcur,
                                                 int* __restrict__ coarse, int nE, int NB) {
    __shared__ int cnt[MAXNB];
    __shared__ int basix[MAXNB];
    const int tid = threadIdx.x;
    for (int i = tid; i < NB; i += 256) cnt[i] = 0;
    __syncthreads();
    int base = blockIdx.x * 4096;
    int es[16], ed[16], rk[16];
#pragma unroll
    for (int i = 0; i < 16; i++) {
        int e = base + i * 256 + tid;
        if (e < nE) {
            es[i] = src[e];
            ed[i] = dst[e];
            rk[i] = atomicAdd(&cnt[ed[i] >> 8], 1);
        } else {
            ed[i] = -1;
        }
    }
    __syncthreads();
    for (int i = tid; i < NB; i += 256)
        if (cnt[i]) basix[i] = atomicAdd(&bcur[i], cnt[i]);
    __syncthreads();
#pragma unroll
    for (int i = 0; i < 16; i++) {
        if (ed[i] >= 0)
            coarse[basix[ed[i] >> 8] + rk[i]] = es[i] | ((ed[i] & 255) << 24);
    }
}

// phase B: per-bucket exact CSR (no intra-row sort)
__global__ __launch_bounds__(256) void bucketB_k(const int* __restrict__ coarse,
                                                 const int* __restrict__ bstart,
                                                 int* __restrict__ rowstart,
                                                 int* __restrict__ col,
                                                 float* __restrict__ dinv, int N) {
    __shared__ int cnt[256];
    __shared__ int s[256];
    __shared__ int cur[256];
    const int tid = threadIdx.x;
    const int b = blockIdx.x;
    const int beg = bstart[b], end = bstart[b + 1];
    cnt[tid] = 0;
    __syncthreads();
    for (int p = beg + tid; p < end; p += 256)
        atomicAdd(&cnt[((uint)coarse[p]) >> 24], 1);
    __syncthreads();
    int c = cnt[tid];
    s[tid] = c;
    __syncthreads();
    for (int off = 1; off < 256; off <<= 1) {
        int v = (tid >= off) ? s[tid - off] : 0;
        __syncthreads();
        s[tid] += v;
        __syncthreads();
    }
    int ex = s[tid] - c;
    int node = b * 256 + tid;
    if (node < N) {
        rowstart[node] = beg + ex;
        dinv[node] = rsqrtf((float)c + 1.0f);  // +1 = self loop
    }
    cur[tid] = ex;
    __syncthreads();
    for (int p = beg + tid; p < end; p += 256) {
        int v = coarse[p];
        int r = atomicAdd(&cur[((uint)v) >> 24], 1);
        col[beg + r] = v & 0xFFFFFF;
    }
}

// ================= weight prep =================
__global__ __launch_bounds__(256) void prep_wt_all_k(const float* __restrict__ W1,
                                                     const float* __restrict__ W2,
                                                     const float* __restrict__ W3,
                                                     const float* __restrict__ W4,
                                                     ushort* __restrict__ T1,
                                                     ushort* __restrict__ T2,
                                                     ushort* __restrict__ T3,
                                                     ushort* __restrict__ T4) {
    int which = blockIdx.x >> 6;
    const float* W = (which == 0) ? W1 : (which == 1) ? W2 : (which == 2) ? W3 : W4;
    ushort* T = (which == 0) ? T1 : (which == 1) ? T2 : (which == 2) ? T3 : T4;
    int i = (blockIdx.x & 63) * 256 + threadIdx.x;  // < 16384
    int n = i >> 7, k = i & 127;
    T[n * 128 + k] = f2bf(W[k * 128 + n]);
}

// ============ gather conv over fp8 h rows ============
// out = relu(bn(dd*(Sum_s dinv[s]*h[s] + dd*h[d]) + bias))
// one wave per node; 16 lanes per edge-row (8 ch/lane, uint2 = 8B), 4 edges/wave-step
__device__ __forceinline__ void acc8_fp8(float* acc, uint2 a, float nn) {
    f32x2 p;
    p = __builtin_amdgcn_cvt_pk_f32_fp8(a.x, false);
    acc[0] = fmaf(p.x, nn, acc[0]); acc[1] = fmaf(p.y, nn, acc[1]);
    p = __builtin_amdgcn_cvt_pk_f32_fp8(a.x, true);
    acc[2] = fmaf(p.x, nn, acc[2]); acc[3] = fmaf(p.y, nn, acc[3]);
    p = __builtin_amdgcn_cvt_pk_f32_fp8(a.y, false);
    acc[4] = fmaf(p.x, nn, acc[4]); acc[5] = fmaf(p.y, nn, acc[5]);
    p = __builtin_amdgcn_cvt_pk_f32_fp8(a.y, true);
    acc[6] = fmaf(p.x, nn, acc[6]); acc[7] = fmaf(p.y, nn, acc[7]);
}

__global__ __launch_bounds__(256) void gather_k(const unsigned char* __restrict__ h8,
                                                const int* __restrict__ rowstart,
                                                const int* __restrict__ col,
                                                const float* __restrict__ dinv,
                                                const float* __restrict__ bias,
                                                const float* __restrict__ g,
                                                const float* __restrict__ be,
                                                const float* __restrict__ mn,
                                                const float* __restrict__ vr,
                                                ushort* __restrict__ out, int n) {
    int node = blockIdx.x * 4 + (threadIdx.x >> 6);
    if (node >= n) return;
    int lane = threadIdx.x & 63;
    int grp = lane >> 4;   // which edge in the 4-edge step
    int li = lane & 15;    // channel group: 8 ch
    int c = li * 8;
    int beg = rowstart[node], end = rowstart[node + 1];
    float dd = dinv[node];
    float acc[8] = {0.f, 0.f, 0.f, 0.f, 0.f, 0.f, 0.f, 0.f};

    if (grp == 0) {  // self loop: dd * h[d] (outer dd applied at the end)
        uint2 rv = *(const uint2*)&h8[(size_t)node * 128 + c];
        acc8_fp8(acc, rv, dd);
    }

    int p = beg + grp;
    for (; p + 4 < end; p += 8) {  // 2 edges per group per iter = 8 edges/wave
        int s0 = __builtin_nontemporal_load(col + p);
        int s1 = __builtin_nontemporal_load(col + p + 4);
        float n0 = dinv[s0], n1 = dinv[s1];
        uint2 a = *(const uint2*)&h8[(size_t)s0 * 128 + c];
        uint2 b = *(const uint2*)&h8[(size_t)s1 * 128 + c];
        acc8_fp8(acc, a, n0);
        acc8_fp8(acc, b, n1);
    }
    if (p < end) {
        int s0 = __builtin_nontemporal_load(col + p);
        float n0 = dinv[s0];
        uint2 a = *(const uint2*)&h8[(size_t)s0 * 128 + c];
        acc8_fp8(acc, a, n0);
    }
    // reduce the 4 lane-groups (lanes l, l+16, l+32, l+48 hold same channels)
#pragma unroll
    for (int j = 0; j < 8; j++) {
        acc[j] += __shfl_xor(acc[j], 16, 64);
        acc[j] += __shfl_xor(acc[j], 32, 64);
    }
    if (grp == 0) {
        uint r[4];
#pragma unroll
        for (int j = 0; j < 4; j++) {
            int cc = c + j * 2;
            float a0 = acc[j * 2] * dd, a1 = acc[j * 2 + 1] * dd;
            float sc0 = g[cc] * rsqrtf(vr[cc] + EPS_BN);
            float sc1 = g[cc + 1] * rsqrtf(vr[cc + 1] + EPS_BN);
            float o0 = fmaxf((a0 + bias[cc] - mn[cc]) * sc0 + be[cc], 0.0f);
            float o1 = fmaxf((a1 + bias[cc + 1] - mn[cc + 1]) * sc1 + be[cc + 1], 0.0f);
            r[j] = (uint)f2bf(o0) | ((uint)f2bf(o1) << 16);
        }
        uint4 rv = {r[0], r[1], r[2], r[3]};
        *(uint4*)&out[(size_t)node * 128 + c] = rv;
    }
}

// ============ MFMA GEMM: Y = X(n,128) @ W(128,128), fused epilogues ============
// MODE 0: raw -> fp8 e4m3   MODE 1: relu(bn(v+bias)) -> bf16
// MODE 2: relu(v+bias) -> f32, PLUS fused head: pred = softplus(h1 @ Wo + bo)
// F32IN: input X is f32 (converted to bf16 during LDS staging)
template <int MODE, int F32IN>
__global__ __launch_bounds__(256) void mfma_gemm_k(const void* __restrict__ Xin,
                                                   const ushort* __restrict__ Wt,
                                                   const float* __restrict__ bias,
                                                   const float* __restrict__ g,
                                                   const float* __restrict__ be,
                                                   const float* __restrict__ mn,
                                                   const float* __restrict__ vr,
                                                   const float* __restrict__ Wo,
                                                   const float* __restrict__ bo,
                                                   float* __restrict__ pred,
                                                   void* __restrict__ Y, int nrows) {
    constexpr int LDK = 136;  // 128 + 8 pad
    __shared__ ushort sX[64 * LDK];
    __shared__ ushort sW[128 * LDK];
    __shared__ float red[64];
    const int tid = threadIdx.x;
    const int row0 = blockIdx.x * 64;

#pragma unroll
    for (int i = 0; i < 8; i++) {
        int c = tid + i * 256;
        int r = c >> 4, o = c & 15;
        *(int4*)&sW[r * LDK + o * 8] = *(const int4*)&Wt[r * 128 + o * 8];
    }
    if (F32IN) {
        const float* Xf = (const float*)Xin;
#pragma unroll
        for (int i = 0; i < 8; i++) {
            int c = tid + i * 256;      // 2048 float4-chunks
            int r = c >> 5, o = c & 31; // 32 float4 per row
            int rg = row0 + r;
            if (rg >= nrows) rg = nrows - 1;
            float4 v = *(const float4*)&Xf[(size_t)rg * 128 + o * 4];
            ushort4 u = {f2bf(v.x), f2bf(v.y), f2bf(v.z), f2bf(v.w)};
            *(ushort4*)&sX[r * LDK + o * 4] = u;
        }
    } else {
        const ushort* Xb = (const ushort*)Xin;
#pragma unroll
        for (int i = 0; i < 4; i++) {
            int c = tid + i * 256;
            int r = c >> 4, o = c & 15;
            int rg = row0 + r;
            if (rg >= nrows) rg = nrows - 1;
            *(int4*)&sX[r * LDK + o * 8] = *(const int4*)&Xb[(size_t)rg * 128 + o * 8];
        }
    }
    if (MODE == 2 && tid < 64) red[tid] = 0.0f;
    __syncthreads();

    const int wave = tid >> 6, lane = tid & 63;
    const int rw = (wave >> 1) * 32;
    const int cw = (wave & 1) * 64;
    const int lm = lane & 15, lq = lane >> 4;

    f32x4 acc[2][4];
#pragma unroll
    for (int tr = 0; tr < 2; tr++)
#pragma unroll
        for (int tc = 0; tc < 4; tc++) acc[tr][tc] = (f32x4){0.f, 0.f, 0.f, 0.f};

#pragma unroll
    for (int ks = 0; ks < 4; ks++) {
        int kb = ks * 32 + lq * 8;
        bf16x8 a[2], b[4];
#pragma unroll
        for (int tr = 0; tr < 2; tr++)
            a[tr] = *(bf16x8*)&sX[(rw + tr * 16 + lm) * LDK + kb];
#pragma unroll
        for (int tc = 0; tc < 4; tc++)
            b[tc] = *(bf16x8*)&sW[(cw + tc * 16 + lm) * LDK + kb];
#pragma unroll
        for (int tr = 0; tr < 2; tr++)
#pragma unroll
            for (int tc = 0; tc < 4; tc++)
                acc[tr][tc] = __builtin_amdgcn_mfma_f32_16x16x32_bf16(a[tr], b[tc],
                                                                      acc[tr][tc], 0, 0, 0);
    }

    float part[8];
    if (MODE == 2) {
#pragma unroll
        for (int i = 0; i < 8; i++) part[i] = 0.0f;
    }
#pragma unroll
    for (int tc = 0; tc < 4; tc++) {
        int c = cw + tc * 16 + lm;
        float psc, psh;
        if (MODE == 1) {
            float sc = g[c] * rsqrtf(vr[c] + EPS_BN);
            psc = sc;
            psh = be[c] + (bias[c] - mn[c]) * sc;
        } else if (MODE == 2) {
            psc = 1.0f;
            psh = bias[c];
        } else {
            psc = 1.0f;
            psh = 0.0f;
        }
        float woc = (MODE == 2) ? Wo[c] : 0.0f;
#pragma unroll
        for (int tr = 0; tr < 2; tr++) {
#pragma unroll
            for (int r = 0; r < 4; r++) {
                int lrow = rw + tr * 16 + lq * 4 + r;
                int row = row0 + lrow;
                if (row < nrows) {
                    float v = acc[tr][tc][r];
                    if (MODE == 0) {
                        ((unsigned char*)Y)[(size_t)row * 128 + c] = f2fp8(v);
                    } else if (MODE == 1) {
                        v = fmaxf(v * psc + psh, 0.0f);
                        ((ushort*)Y)[(size_t)row * 128 + c] = f2bf(v);
                    } else {
                        v = fmaxf(v + psh, 0.0f);
                        ((float*)Y)[(size_t)row * 128 + c] = v;
                        part[tr * 4 + r] = fmaf(v, woc, part[tr * 4 + r]);
                    }
                }
            }
        }
    }
    if (MODE == 2) {
#pragma unroll
        for (int tr = 0; tr < 2; tr++)
#pragma unroll
            for (int r = 0; r < 4; r++)
                atomicAdd(&red[rw + tr * 16 + lq * 4 + r], part[tr * 4 + r]);
        __syncthreads();
        if (tid < 64) {
            int row = row0 + tid;
            if (row < nrows) {
                float xv = red[tid] + bo[0];
                pred[row] = fmaxf(xv, 0.0f) + log1pf(expf(-fabsf(xv)));  // softplus
            }
        }
    }
}

extern "C" void kernel_launch(void* const* d_in, const int* in_sizes, int n_in,
                              void* d_out, int out_size, void* d_ws, size_t ws_size,
                              hipStream_t stream) {
    const float* x = (const float*)d_in[0];
    const int* ei = (const int*)d_in[1];
    const int N = in_sizes[0] / 128;
    const int E = in_sizes[1] / 2;
    const int* srcv = ei;
    const int* dstv = ei + E;
    const float* W1 = (const float*)d_in[2];  const float* b1 = (const float*)d_in[3];
    const float* W2 = (const float*)d_in[4];  const float* b2 = (const float*)d_in[5];
    const float* Wf1 = (const float*)d_in[6]; const float* bf1 = (const float*)d_in[7];
    const float* Wf2 = (const float*)d_in[8]; const float* bf2 = (const float*)d_in[9];
    const float* Wo = (const float*)d_in[10]; const float* bo = (const float*)d_in[11];
    const float* g1 = (const float*)d_in[12], *be1 = (const float*)d_in[13],
               *m1 = (const float*)d_in[14], *v1 = (const float*)d_in[15];
    const float* g2 = (const float*)d_in[16], *be2 = (const float*)d_in[17],
               *m2 = (const float*)d_in[18], *v2 = (const float*)d_in[19];
    const float* g3 = (const float*)d_in[20], *be3 = (const float*)d_in[21],
               *m3 = (const float*)d_in[22], *v3 = (const float*)d_in[23];

    // ---- workspace carve-up ----
    char* ws = (char*)d_ws;
    size_t off = 0;
    auto carve = [&](size_t bytes) {
        char* p = ws + off;
        off = (off + bytes + 255) & ~(size_t)255;
        return p;
    };
    const int NB = (N + 255) >> 8;
    int* bcnt = (int*)carve((size_t)MAXNB * 4);
    int* bstart = (int*)carve((size_t)(MAXNB + 1) * 4);
    int* bcur = (int*)carve((size_t)MAXNB * 4);
    int* rowstart = (int*)carve((size_t)(N + 1) * 4);
    int* col = (int*)carve((size_t)E * 4);
    int* coarse = (int*)carve((size_t)E * 4);
    float* dinv = (float*)carve((size_t)N * 4);
    unsigned char* bufA8 = (unsigned char*)carve((size_t)N * 128);  // fp8 h
    ushort* bufB = (ushort*)carve((size_t)N * 128 * 2);             // bf16
    ushort* bufC = (ushort*)carve((size_t)N * 128 * 2);             // bf16
    ushort* Wt1 = (ushort*)carve(128 * 128 * 2);
    ushort* Wt2 = (ushort*)carve(128 * 128 * 2);
    ushort* Wtf1 = (ushort*)carve(128 * 128 * 2);
    ushort* Wtf2 = (ushort*)carve(128 * 128 * 2);

    float* out_pred = (float*)d_out;
    float* out_h1 = out_pred + N;

    const int gblocks = (N + 63) / 64;
    const int tblocks = (E + 4095) / 4096;
    const int wblocks = (N + 3) / 4;

    // ---- bucketed CSR build ----
    hipMemsetAsync(bcnt, 0, (size_t)MAXNB * 4, stream);
    chist_k<<<tblocks, 256, 0, stream>>>(dstv, bcnt, E, NB);
    cscan_k<<<1, 512, 0, stream>>>(bcnt, bstart, bcur, rowstart, NB, E, N);
    bucketA_k<<<tblocks, 256, 0, stream>>>(srcv, dstv, bcur, coarse, E, NB);
    bucketB_k<<<NB, 256, 0, stream>>>(coarse, bstart, rowstart, col, dinv, N);

    // ---- weight prep ----
    prep_wt_all_k<<<256, 256, 0, stream>>>(W1, W2, Wf1, Wf2, Wt1, Wt2, Wtf1, Wtf2);

    // layer 1: h = x@W1 (fp8); conv+bn+relu -> bf16
    mfma_gemm_k<0, 1><<<gblocks, 256, 0, stream>>>(x, Wt1, nullptr, nullptr, nullptr,
                                                   nullptr, nullptr, nullptr, nullptr,
                                                   nullptr, bufA8, N);
    gather_k<<<wblocks, 256, 0, stream>>>(bufA8, rowstart, col, dinv, b1, g1, be1, m1, v1,
                                          bufB, N);

    // layer 2
    mfma_gemm_k<0, 0><<<gblocks, 256, 0, stream>>>(bufB, Wt2, nullptr, nullptr, nullptr,
                                                   nullptr, nullptr, nullptr, nullptr,
                                                   nullptr, bufA8, N);
    gather_k<<<wblocks, 256, 0, stream>>>(bufA8, rowstart, col, dinv, b2, g2, be2, m2, v2,
                                          bufB, N);

    // layer 3: h = relu(bn3(h@Wf1 + bf1))
    mfma_gemm_k<1, 0><<<gblocks, 256, 0, stream>>>(bufB, Wtf1, bf1, g3, be3, m3, v3,
                                                   nullptr, nullptr, nullptr, bufC, N);

    // layer 4 + head: h1 = relu(h@Wf2 + bf2) -> f32 d_out; pred = softplus(h1@Wo+bo)
    mfma_gemm_k<2, 0><<<gblocks, 256, 0, stream>>>(bufC, Wtf2, bf2, nullptr, nullptr,
                                                   nullptr, nullptr, Wo, bo, out_pred,
                                                   out_h1, N);
}